// Round 2
// baseline (98.660 us; speedup 1.0000x reference)
//
#include <hip/hip_runtime.h>
#include <hip/hip_bf16.h>

#define V_   163842
#define K_   6
#define G_   5
#define N_   2
#define CIN  32
#define COUT 64
#define CG   160   // CIN * G_
#define TV   64    // vertices per block
#define CGP  168   // padded CG (21*16B rows; stride 336B -> only ~2-way bank aliasing)

typedef __attribute__((ext_vector_type(8))) short bf16x8;
typedef __attribute__((ext_vector_type(4))) float f32x4;

__device__ __forceinline__ float bf2f(unsigned int u16) {
  union { unsigned int u; float f; } c; c.u = u16 << 16; return c.f;
}
__device__ __forceinline__ unsigned short f2bf(float f) {
  union { float f; unsigned int u; } c; c.f = f;
  unsigned int r = c.u + 0x7fffu + ((c.u >> 16) & 1u);
  return (unsigned short)(r >> 16);
}

// x[n][c][v] fp32 -> xt[n][v][c] bf16  (coalesced reads over v; 64B/vertex writes)
__global__ __launch_bounds__(256) void transpose_kernel(const float* __restrict__ x,
                                                        unsigned short* __restrict__ xt) {
  int v = blockIdx.x * 256 + threadIdx.x;
  int n = blockIdx.y;
  if (v >= V_) return;
  const float* xp = x + (size_t)n * CIN * V_ + v;
  unsigned int words[16];
#pragma unroll
  for (int w = 0; w < 16; ++w) {
    float a = xp[(size_t)(2 * w) * V_];
    float b = xp[(size_t)(2 * w + 1) * V_];
    words[w] = (unsigned int)f2bf(a) | ((unsigned int)f2bf(b) << 16);
  }
  uint4* dst = (uint4*)(xt + ((size_t)n * V_ + v) * CIN);
#pragma unroll
  for (int i = 0; i < 4; ++i)
    dst[i] = make_uint4(words[4 * i], words[4 * i + 1], words[4 * i + 2], words[4 * i + 3]);
}

__global__ __launch_bounds__(512, 6) void icoconv_kernel(
    const unsigned short* __restrict__ xt,
    const int* __restrict__ nbr,
    const float* __restrict__ gw,
    const float* __restrict__ convw,
    const float* __restrict__ convb,
    float* __restrict__ out) {
  __shared__ int   idx_s[TV * K_];
  __shared__ float gw_s[TV * G_ * K_];
  __shared__ __align__(16) unsigned short G_s[N_][TV][CGP];

  const int t  = threadIdx.x;
  const int v0 = blockIdx.x * TV;

  // ---- stage 0: cooperative coalesced load of idx + grad_w into LDS ----
  for (int i = t; i < TV * K_; i += 512) {
    int gi = v0 * K_ + i;
    idx_s[i] = (gi < V_ * K_) ? nbr[gi] : 0;
  }
  for (int i = t; i < TV * G_ * K_; i += 512) {
    int gi = v0 * G_ * K_ + i;
    gw_s[i] = (gi < V_ * G_ * K_) ? gw[gi] : 0.0f;  // zero weights => zero grads for tail v
  }
  __syncthreads();

  // ---- stage 1: gather + grads (fp32 accum), write bf16 tile to LDS ----
  // thread t -> c-pair cp = t&15 (c = 2cp, 2cp+1), vertex rows vl = (t>>4) + 32*pass
  const int cp = t & 15;
  const unsigned short* xt0 = xt;
  const unsigned short* xt1 = xt + (size_t)V_ * CIN;
#pragma unroll
  for (int pass = 0; pass < 2; ++pass) {
    const int vl = (t >> 4) + pass * 32;

    // hoist indices, then issue all 12 gather loads before consuming
    int j[K_];
#pragma unroll
    for (int k = 0; k < K_; ++k) j[k] = idx_s[vl * K_ + k];
    unsigned int u0[K_], u1[K_];
#pragma unroll
    for (int k = 0; k < K_; ++k) {
      u0[k] = *(const unsigned int*)(xt0 + (size_t)j[k] * CIN + 2 * cp);
      u1[k] = *(const unsigned int*)(xt1 + (size_t)j[k] * CIN + 2 * cp);
    }

    float acc[N_][2][G_];
#pragma unroll
    for (int n = 0; n < N_; ++n)
#pragma unroll
      for (int c01 = 0; c01 < 2; ++c01)
#pragma unroll
        for (int g = 0; g < G_; ++g) acc[n][c01][g] = 0.0f;

#pragma unroll
    for (int k = 0; k < K_; ++k) {
      const float x00 = bf2f(u0[k] & 0xffffu), x01 = bf2f(u0[k] >> 16);
      const float x10 = bf2f(u1[k] & 0xffffu), x11 = bf2f(u1[k] >> 16);
#pragma unroll
      for (int g = 0; g < G_; ++g) {
        const float w = gw_s[vl * (G_ * K_) + g * K_ + k];
        acc[0][0][g] += x00 * w;
        acc[0][1][g] += x01 * w;
        acc[1][0][g] += x10 * w;
        acc[1][1][g] += x11 * w;
      }
    }
    // pack 10 bf16 (c=2cp:g0..4, c=2cp+1:g0..4) -> 5 dwords, contiguous at cg = 10*cp
#pragma unroll
    for (int n = 0; n < N_; ++n) {
      unsigned short h[10];
#pragma unroll
      for (int c01 = 0; c01 < 2; ++c01)
#pragma unroll
        for (int g = 0; g < G_; ++g) h[c01 * G_ + g] = f2bf(acc[n][c01][g]);
      unsigned int* dst = (unsigned int*)&G_s[n][vl][cp * 10];
#pragma unroll
      for (int i = 0; i < 5; ++i)
        dst[i] = (unsigned int)h[2 * i] | ((unsigned int)h[2 * i + 1] << 16);
    }
  }
  __syncthreads();

  // ---- stage 2: out[64o x 64v] = W(64x160) @ G(160x64) + b, via MFMA 16x16x32 ----
  // 8 waves; wave w owns o-tile (w&3) and v-tiles {w>>1... } -> vt in {w>>2, (w>>2)+2}
  const int lane = t & 63;
  const int wave = t >> 6;
  const int o0   = (wave & 3) * 16;
  const int vtb  = wave >> 2;   // 0 or 1
  const int row  = lane & 15;   // A row (o), B col (v), D col (v)
  const int kg   = lane >> 4;   // k-group: 8 contiguous K per 16-lane group

  // A fragments: W[o0+row][ks*32 + kg*8 + e], fp32 -> bf16, held in regs
  bf16x8 afrag[5];
#pragma unroll
  for (int ks = 0; ks < 5; ++ks) {
    const float* wp = convw + (size_t)(o0 + row) * CG + ks * 32 + kg * 8;
    const float4 lo = *(const float4*)wp;
    const float4 hi = *(const float4*)(wp + 4);
    bf16x8 a;
    a[0] = (short)f2bf(lo.x); a[1] = (short)f2bf(lo.y);
    a[2] = (short)f2bf(lo.z); a[3] = (short)f2bf(lo.w);
    a[4] = (short)f2bf(hi.x); a[5] = (short)f2bf(hi.y);
    a[6] = (short)f2bf(hi.z); a[7] = (short)f2bf(hi.w);
    afrag[ks] = a;
  }
  float bias[4];
#pragma unroll
  for (int r = 0; r < 4; ++r) bias[r] = convb[o0 + kg * 4 + r];

#pragma unroll
  for (int n = 0; n < N_; ++n) {
#pragma unroll
    for (int vh = 0; vh < 2; ++vh) {
      const int vt = vtb + vh * 2;
      f32x4 acc = {bias[0], bias[1], bias[2], bias[3]};
#pragma unroll
      for (int ks = 0; ks < 5; ++ks) {
        bf16x8 bfrag = *(const bf16x8*)(&G_s[n][vt * 16 + row][ks * 32 + kg * 8]);
        acc = __builtin_amdgcn_mfma_f32_16x16x32_bf16(afrag[ks], bfrag, acc, 0, 0, 0);
      }
      const int v = v0 + vt * 16 + row;
      if (v < V_) {
#pragma unroll
        for (int r = 0; r < 4; ++r)
          out[(size_t)(n * COUT + o0 + kg * 4 + r) * V_ + v] = acc[r];
      }
    }
  }
}

extern "C" void kernel_launch(void* const* d_in, const int* in_sizes, int n_in,
                              void* d_out, int out_size, void* d_ws, size_t ws_size,
                              hipStream_t stream) {
  const float* x     = (const float*)d_in[0];
  const int*   nbr   = (const int*)d_in[1];
  const float* gw    = (const float*)d_in[2];
  const float* convw = (const float*)d_in[3];
  const float* convb = (const float*)d_in[4];
  float* out = (float*)d_out;
  unsigned short* xt = (unsigned short*)d_ws;  // N*V*CIN bf16 = 21 MB

  dim3 tg((V_ + 255) / 256, N_);
  transpose_kernel<<<tg, 256, 0, stream>>>(x, xt);

  const int nblk = (V_ + TV - 1) / TV;
  icoconv_kernel<<<nblk, 512, 0, stream>>>(xt, nbr, gw, convw, convb, out);
}

// Round 3
// 72.833 us; speedup vs baseline: 1.3546x; 1.3546x over previous
//
#include <hip/hip_runtime.h>
#include <hip/hip_bf16.h>

#define V_   163842
#define K_   6
#define G_   5
#define N_   2
#define CIN  32
#define COUT 64
#define CG   160   // CIN * G_
#define TV   64    // vertices per block
#define CGP  168   // padded CG (stride 336B -> ~2-way bank aliasing on b128 reads)

typedef __attribute__((ext_vector_type(8))) short bf16x8;
typedef __attribute__((ext_vector_type(4))) float f32x4;

__device__ __forceinline__ float bf2f(unsigned int u16) {
  union { unsigned int u; float f; } c; c.u = u16 << 16; return c.f;
}
__device__ __forceinline__ unsigned short f2bf(float f) {
  union { float f; unsigned int u; } c; c.f = f;
  unsigned int r = c.u + 0x7fffu + ((c.u >> 16) & 1u);
  return (unsigned short)(r >> 16);
}

// x[n][c][v] fp32 -> xt[v][c][n] bf16 (both batches interleaved: 128B per vertex,
// so each gather of a vertex is ONE cache line instead of two 64B lines 10MB apart)
__global__ __launch_bounds__(256) void transpose_kernel(const float* __restrict__ x,
                                                        unsigned short* __restrict__ xt) {
  int v = blockIdx.x * 256 + threadIdx.x;
  if (v >= V_) return;
  const float* x0 = x + v;                       // n=0, c-major stride V_
  const float* x1 = x + (size_t)CIN * V_ + v;    // n=1
  unsigned int words[CIN];
#pragma unroll
  for (int c = 0; c < CIN; ++c) {
    float a = x0[(size_t)c * V_];
    float b = x1[(size_t)c * V_];
    words[c] = (unsigned int)f2bf(a) | ((unsigned int)f2bf(b) << 16);  // (n0, n1)
  }
  uint4* dst = (uint4*)(xt + (size_t)v * (2 * CIN));
#pragma unroll
  for (int i = 0; i < 8; ++i)
    dst[i] = make_uint4(words[4 * i], words[4 * i + 1], words[4 * i + 2], words[4 * i + 3]);
}

__global__ __launch_bounds__(256) void icoconv_kernel(
    const unsigned short* __restrict__ xt,
    const int* __restrict__ nbr,
    const float* __restrict__ gw,
    const float* __restrict__ convw,
    const float* __restrict__ convb,
    float* __restrict__ out) {
  __shared__ int   idx_s[TV * K_];
  __shared__ float gw_s[TV * G_ * K_];
  __shared__ __align__(16) unsigned short G_s[N_][TV][CGP];

  const int t  = threadIdx.x;
  const int v0 = blockIdx.x * TV;

  // ---- stage 0: cooperative coalesced load of idx + grad_w into LDS ----
  for (int i = t; i < TV * K_; i += 256) {
    int gi = v0 * K_ + i;
    idx_s[i] = (gi < V_ * K_) ? nbr[gi] : 0;
  }
  for (int i = t; i < TV * G_ * K_; i += 256) {
    int gi = v0 * G_ * K_ + i;
    gw_s[i] = (gi < V_ * G_ * K_) ? gw[gi] : 0.0f;  // zero weights => zero grads for tail v
  }
  __syncthreads();

  // ---- stage 1: gather + grads (fp32 accum), write bf16 tile to LDS ----
  // thread t -> c-pair cp = t&15 (c = 2cp, 2cp+1), vertex rows vl = (t>>4) + 16*pass
  // ONE dwordx2 per (vertex,neighbor) covers both batches and both channels.
  const int cp = t & 15;
#pragma unroll
  for (int pass = 0; pass < 4; ++pass) {
    const int vl = (t >> 4) + pass * 16;

    int j[K_];
#pragma unroll
    for (int k = 0; k < K_; ++k) j[k] = idx_s[vl * K_ + k];
    uint2 u[K_];
#pragma unroll
    for (int k = 0; k < K_; ++k)
      u[k] = *(const uint2*)(xt + (size_t)j[k] * (2 * CIN) + 4 * cp);

    float acc[N_][2][G_];
#pragma unroll
    for (int n = 0; n < N_; ++n)
#pragma unroll
      for (int c01 = 0; c01 < 2; ++c01)
#pragma unroll
        for (int g = 0; g < G_; ++g) acc[n][c01][g] = 0.0f;

#pragma unroll
    for (int k = 0; k < K_; ++k) {
      const float x00 = bf2f(u[k].x & 0xffffu);  // n0, c=2cp
      const float x10 = bf2f(u[k].x >> 16);      // n1, c=2cp
      const float x01 = bf2f(u[k].y & 0xffffu);  // n0, c=2cp+1
      const float x11 = bf2f(u[k].y >> 16);      // n1, c=2cp+1
#pragma unroll
      for (int g = 0; g < G_; ++g) {
        const float w = gw_s[vl * (G_ * K_) + g * K_ + k];
        acc[0][0][g] += x00 * w;
        acc[0][1][g] += x01 * w;
        acc[1][0][g] += x10 * w;
        acc[1][1][g] += x11 * w;
      }
    }
    // pack 10 bf16 (c=2cp:g0..4, c=2cp+1:g0..4) -> 5 dwords, contiguous at cg = 10*cp
#pragma unroll
    for (int n = 0; n < N_; ++n) {
      unsigned short h[10];
#pragma unroll
      for (int c01 = 0; c01 < 2; ++c01)
#pragma unroll
        for (int g = 0; g < G_; ++g) h[c01 * G_ + g] = f2bf(acc[n][c01][g]);
      unsigned int* dst = (unsigned int*)&G_s[n][vl][cp * 10];
#pragma unroll
      for (int i = 0; i < 5; ++i)
        dst[i] = (unsigned int)h[2 * i] | ((unsigned int)h[2 * i + 1] << 16);
    }
  }
  __syncthreads();

  // ---- stage 2: out[64o x 64v] = W(64x160) @ G(160x64) + b, via MFMA 16x16x32 ----
  const int lane = t & 63;
  const int wave = t >> 6;
  const int o0   = wave * 16;
  const int row  = lane & 15;   // A row (o), B col (v), D col (v)
  const int kg   = lane >> 4;   // k-group: 8 contiguous K per 16-lane group

  bf16x8 afrag[5];
#pragma unroll
  for (int ks = 0; ks < 5; ++ks) {
    const float* wp = convw + (size_t)(o0 + row) * CG + ks * 32 + kg * 8;
    const float4 lo = *(const float4*)wp;
    const float4 hi = *(const float4*)(wp + 4);
    bf16x8 a;
    a[0] = (short)f2bf(lo.x); a[1] = (short)f2bf(lo.y);
    a[2] = (short)f2bf(lo.z); a[3] = (short)f2bf(lo.w);
    a[4] = (short)f2bf(hi.x); a[5] = (short)f2bf(hi.y);
    a[6] = (short)f2bf(hi.z); a[7] = (short)f2bf(hi.w);
    afrag[ks] = a;
  }
  float bias[4];
#pragma unroll
  for (int r = 0; r < 4; ++r) bias[r] = convb[o0 + kg * 4 + r];

#pragma unroll
  for (int n = 0; n < N_; ++n) {
#pragma unroll
    for (int vt = 0; vt < 4; ++vt) {
      f32x4 acc = {bias[0], bias[1], bias[2], bias[3]};
#pragma unroll
      for (int ks = 0; ks < 5; ++ks) {
        bf16x8 bfrag = *(const bf16x8*)(&G_s[n][vt * 16 + row][ks * 32 + kg * 8]);
        acc = __builtin_amdgcn_mfma_f32_16x16x32_bf16(afrag[ks], bfrag, acc, 0, 0, 0);
      }
      const int v = v0 + vt * 16 + row;
      if (v < V_) {
#pragma unroll
        for (int r = 0; r < 4; ++r)
          out[(size_t)(n * COUT + o0 + kg * 4 + r) * V_ + v] = acc[r];
      }
    }
  }
}

extern "C" void kernel_launch(void* const* d_in, const int* in_sizes, int n_in,
                              void* d_out, int out_size, void* d_ws, size_t ws_size,
                              hipStream_t stream) {
  const float* x     = (const float*)d_in[0];
  const int*   nbr   = (const int*)d_in[1];
  const float* gw    = (const float*)d_in[2];
  const float* convw = (const float*)d_in[3];
  const float* convb = (const float*)d_in[4];
  float* out = (float*)d_out;
  unsigned short* xt = (unsigned short*)d_ws;  // V*64 bf16 (n-interleaved) = 21 MB

  transpose_kernel<<<(V_ + 255) / 256, 256, 0, stream>>>(x, xt);

  const int nblk = (V_ + TV - 1) / TV;
  icoconv_kernel<<<nblk, 256, 0, stream>>>(xt, nbr, gw, convw, convb, out);
}